// Round 11
// baseline (2140.257 us; speedup 1.0000x reference)
//
#include <hip/hip_runtime.h>
#include <hip/hip_bf16.h>

typedef __hip_bfloat16 bf16;
typedef __attribute__((ext_vector_type(8))) short short8;
typedef __attribute__((ext_vector_type(4))) short short4v;
typedef __attribute__((ext_vector_type(4))) float f32x4;

#define MFMA(va, vb, vc) \
  __builtin_amdgcn_mfma_f32_16x16x32_bf16(va, vb, vc, 0, 0, 0)

__device__ __forceinline__ float to_f(float x) { return x; }
__device__ __forceinline__ float to_f(bf16 x) { return __bfloat162float(x); }
__device__ __forceinline__ float ldp(const void* p, size_t i, bool f32) {
  return f32 ? ((const float*)p)[i] : __bfloat162float(((const bf16*)p)[i]);
}
__device__ __forceinline__ short f2b(float f) {
  bf16 h = __float2bfloat16(f);
  return *reinterpret_cast<short*>(&h);
}
__device__ __forceinline__ float b2f(short s_) {
  unsigned int ui = ((unsigned int)(unsigned short)s_) << 16;
  float f;
  __builtin_memcpy(&f, &ui, 4);
  return f;
}
// gate-interleave permutation: c = g*256+i -> 64*(i>>4) + 16*g + (i&15).
// MFMA n-subtile j == gate in fused cell kernels.
__device__ __forceinline__ int perm1024(int c) {
  return ((c & 255) >> 4) * 64 + (c >> 8) * 16 + (c & 15);
}

// dtype probe: f32 data read as u16 pairs shows implausible bf16 exponents.
__global__ void detect_kernel(const void* __restrict__ probe,
                              unsigned* __restrict__ flag) {
  __shared__ int sbad;
  if (threadIdx.x == 0) sbad = 0;
  __syncthreads();
  const unsigned short* u = (const unsigned short*)probe;
  int bad = 0;
  for (int i = threadIdx.x; i < 2048; i += 256) {
    unsigned short w = u[i];
    unsigned e = (w >> 7) & 0xFFu;
    bool plaus = (w == 0) || (w == 0x8000u) || (e >= 0x60u && e <= 0x7Eu);
    if (!plaus) bad++;
  }
  atomicAdd(&sbad, bad);
  __syncthreads();
  if (threadIdx.x == 0) *flag = (sbad > 100) ? 1u : 0u;
}

// ---- weight prep ----
// transp: 0=copy, 1=transpose, 2=transpose+perm1024, 3=copy+perm1024
#define MAXSEG 24
struct PrepArgs {
  int nseg;
  const void* src[MAXSEG];
  long long soff[MAXSEG];
  short* dst[MAXSEG];
  int scols[MAXSEG];
  int dstride[MAXSEG];
  int transp[MAXSEG];
  long long prefix[MAXSEG + 1];
};
__global__ void prep_kernel(PrepArgs a, const unsigned* __restrict__ dflag) {
  const bool isf32 = (*dflag != 0u);
  long long i = (long long)blockIdx.x * 256 + threadIdx.x;
  if (i >= a.prefix[a.nseg]) return;
  int s = 0;
  while (i >= a.prefix[s + 1]) s++;
  long long loc = i - a.prefix[s];
  long long r = loc / a.scols[s], c = loc % a.scols[s];
  float v = a.src[s] ? ldp(a.src[s], (size_t)(a.soff[s] + loc), isf32) : 0.f;
  int tp = a.transp[s];
  long long idx;
  if (tp == 1)
    idx = c * a.dstride[s] + r;
  else if (tp == 2)
    idx = (long long)perm1024((int)c) * a.dstride[s] + r;
  else if (tp == 3)
    idx = perm1024((int)c);
  else
    idx = r * a.dstride[s] + c;
  a.dst[s][idx] = f2b(v);
}

// ---- multi-job MFMA GEMM, 128x128 tile (tables, mid, logits) ----
struct GJob {
  const bf16* A;
  const short* WT;
  const bf16* bias;
  float* Cf;
  bf16* Ch;
  const float* Cin;   // optional f32 addend, stride N
  const int* cinrow;  // optional row gather for Cin
  int lda, wst, K, M, N, flags;  // flags: 4=tanh
};
struct GJobs {
  GJob j[4];
};

__global__ __launch_bounds__(256) void mj_gemm(GJobs args) {
  GJob jb = args.j[blockIdx.z];
  const int n0 = blockIdx.x * 128, m0 = blockIdx.y * 128;
  if (n0 >= jb.N || m0 >= jb.M) return;
  __shared__ short As[128][40];
  __shared__ short Bs[128][40];
  const int tid = threadIdx.x, lane = tid & 63, wave = tid >> 6;
  const int srow = tid >> 1, skoff = (tid & 1) * 16;
  const int wr = (wave >> 1) * 64, wc = (wave & 1) * 64;

  const short* abase =
      (const short*)jb.A + (long long)(m0 + srow) * jb.lda + skoff;
  const short* bbase = jb.WT + (long long)(n0 + srow) * jb.wst + skoff;
  f32x4 acc[4][4];
#pragma unroll
  for (int i = 0; i < 4; i++)
#pragma unroll
    for (int j = 0; j < 4; j++) acc[i][j] = 0.f;

  short8 a0 = *(const short8*)(abase);
  short8 a1 = *(const short8*)(abase + 8);
  short8 b0 = *(const short8*)(bbase);
  short8 b1 = *(const short8*)(bbase + 8);
  for (int k0 = 0; k0 < jb.K; k0 += 32) {
    __syncthreads();
    *(short8*)&As[srow][skoff] = a0;
    *(short8*)&As[srow][skoff + 8] = a1;
    *(short8*)&Bs[srow][skoff] = b0;
    *(short8*)&Bs[srow][skoff + 8] = b1;
    __syncthreads();
    int kn = (k0 + 32 < jb.K) ? k0 + 32 : k0;  // clamped prefetch
    a0 = *(const short8*)(abase + kn);
    a1 = *(const short8*)(abase + kn + 8);
    b0 = *(const short8*)(bbase + kn);
    b1 = *(const short8*)(bbase + kn + 8);
    short8 af[4], bfr[4];
#pragma unroll
    for (int i = 0; i < 4; i++)
      af[i] = *(short8*)&As[wr + i * 16 + (lane & 15)][(lane >> 4) * 8];
#pragma unroll
    for (int j = 0; j < 4; j++)
      bfr[j] = *(short8*)&Bs[wc + j * 16 + (lane & 15)][(lane >> 4) * 8];
#pragma unroll
    for (int i = 0; i < 4; i++)
#pragma unroll
      for (int j = 0; j < 4; j++) acc[i][j] = MFMA(af[i], bfr[j], acc[i][j]);
  }
  const int N = jb.N;
  const float* cin = jb.Cin;
  const int* cri = jb.cinrow;
#pragma unroll
  for (int j = 0; j < 4; j++) {
    int col = n0 + wc + j * 16 + (lane & 15);
    float bv = jb.bias ? to_f(jb.bias[col]) : 0.f;
#pragma unroll
    for (int i = 0; i < 4; i++) {
#pragma unroll
      for (int r = 0; r < 4; r++) {
        int row = m0 + wr + i * 16 + (lane >> 4) * 4 + r;
        float v = acc[i][j][r] + bv;
        if (cin) {
          long long crow = cri ? (long long)cri[row] : (long long)row;
          v += cin[crow * N + col];
        }
        if (jb.flags & 4) v = tanhf(v);
        if (jb.Cf) jb.Cf[(long long)row * N + col] = v;
        if (jb.Ch) jb.Ch[(long long)row * N + col] = __float2bfloat16(v);
      }
    }
  }
}

// ---- encoder fused GEMM + GRU cell (round-2 proven kernel) ----
struct CJob {
  const bf16* A;
  const short* WT;
  const bf16* bias;
  const int* tok;
  const bf16* giTab;  // [vocab][768] gate-major (incl bih)
  float* hF;
  bf16* hBf;
  bf16* out2;  // bse slice
  long long out2s;
  int lda, wst, K, hstride, hoff;
};
struct CJobs {
  CJob j[2];
};

__global__ __launch_bounds__(256) void mj_gemm_cell(CJobs args) {
  CJob jb = args.j[blockIdx.z];
  const int n0 = blockIdx.x * 128, m0 = blockIdx.y * 128;
  __shared__ short As[128][40];
  __shared__ short Bs[128][40];
  __shared__ int toks[128];
  const int tid = threadIdx.x, lane = tid & 63, wave = tid >> 6;
  const int srow = tid >> 1, skoff = (tid & 1) * 16;
  const int wr = (wave >> 1) * 64, wcq = (wave & 1) * 64;

  if (tid < 128) toks[tid] = jb.tok[m0 + tid];
  const short* abase =
      (const short*)jb.A + (long long)(m0 + srow) * jb.lda + skoff;
  const short* bbase = jb.WT + (long long)(n0 + srow) * jb.wst + skoff;

  f32x4 acc[4][4];
#pragma unroll
  for (int i = 0; i < 4; i++)
#pragma unroll
    for (int j = 0; j < 4; j++) acc[i][j] = 0.f;

  short8 a0 = *(const short8*)(abase);
  short8 a1 = *(const short8*)(abase + 8);
  short8 b0 = *(const short8*)(bbase);
  short8 b1 = *(const short8*)(bbase + 8);
  for (int k0 = 0; k0 < jb.K; k0 += 32) {
    __syncthreads();
    *(short8*)&As[srow][skoff] = a0;
    *(short8*)&As[srow][skoff + 8] = a1;
    *(short8*)&Bs[srow][skoff] = b0;
    *(short8*)&Bs[srow][skoff + 8] = b1;
    __syncthreads();
    int kn = (k0 + 32 < jb.K) ? k0 + 32 : k0;
    a0 = *(const short8*)(abase + kn);
    a1 = *(const short8*)(abase + kn + 8);
    b0 = *(const short8*)(bbase + kn);
    b1 = *(const short8*)(bbase + kn + 8);
    short8 af[4], bfr[4];
#pragma unroll
    for (int i = 0; i < 4; i++)
      af[i] = *(short8*)&As[wr + i * 16 + (lane & 15)][(lane >> 4) * 8];
#pragma unroll
    for (int j = 0; j < 4; j++)
      bfr[j] = *(short8*)&Bs[wcq + j * 16 + (lane & 15)][(lane >> 4) * 8];
#pragma unroll
    for (int i = 0; i < 4; i++)
#pragma unroll
      for (int j = 0; j < 4; j++) acc[i][j] = MFMA(af[i], bfr[j], acc[i][j]);
  }

  const int u = lane & 15, hi4 = (lane >> 4) * 4;
  const int i_h = ((n0 + wcq) >> 6) * 16 + u;
  const float b0g = to_f(jb.bias[n0 + wcq + u]);
  const float b1g = to_f(jb.bias[n0 + wcq + 16 + u]);
  const float b2g = to_f(jb.bias[n0 + wcq + 32 + u]);
#pragma unroll
  for (int i = 0; i < 4; i++) {
#pragma unroll
    for (int r = 0; r < 4; r++) {
      int row = m0 + wr + i * 16 + hi4 + r;
      const bf16* gi = jb.giTab + (long long)toks[row - m0] * 768 + i_h;
      float ir = to_f(gi[0]), iz = to_f(gi[256]), in_ = to_f(gi[512]);
      float hr = acc[i][0][r] + b0g;
      float hz = acc[i][1][r] + b1g;
      float hn = acc[i][2][r] + b2g;
      long long hidx = (long long)row * jb.hstride + jb.hoff + i_h;
      float hv = jb.hF[hidx];
      float rr = 1.f / (1.f + expf(-(ir + hr)));
      float zz = 1.f / (1.f + expf(-(iz + hz)));
      float nn = tanhf(in_ + rr * hn);
      float o = (1.f - zz) * nn + zz * hv;
      jb.hF[hidx] = o;
      jb.hBf[hidx] = __float2bfloat16(o);
      jb.out2[(long long)row * jb.out2s + i_h] = __float2bfloat16(o);
    }
  }
}

// ---- attention v4: hwh computed in-kernel with 4-row reuse.
// 512 blocks x 4 rows. WhK kept row-major [k][col] so matvec loads are
// coalesced (thread=col) and each block reads WhK once (L2-resident).
struct A4Args {
  const bf16* h;     // [2048][256] current hidden (bf16)
  const short* WhK;  // [256][256] attn_Wh row-major [k][col]
  const bf16* proj;  // [2048*24][256] includes attn_b
  const bf16* bse;   // [2048][24*512]
  const void* v;
  const unsigned* dflag;
  bf16* xr;  // xgcAll t slice base, stride 768, writes cols 0:512
};
__global__ __launch_bounds__(256) void attn4_kernel(A4Args a) {
  const int b0 = blockIdx.x * 4, tid = threadIdx.x;
  const int wave = tid >> 6, lane = tid & 63;
  __shared__ short hsh[4][256];
  __shared__ float hwL[4][256];
  __shared__ float esc[4][24];
  __shared__ float aw[4][24];
  const bool isf32 = (*a.dflag != 0u);
  // stage 4 h rows (8B per thread)
  {
    int r = tid >> 6, c4 = (tid & 63) * 4;
    *(short4v*)&hsh[r][c4] =
        *(const short4v*)((const short*)a.h + (size_t)(b0 + r) * 256 + c4);
  }
  __syncthreads();
  // hwh matvec: thread owns col=tid, 4 rows (WhK coalesced, h broadcast)
  {
    float a0 = 0.f, a1 = 0.f, a2 = 0.f, a3 = 0.f;
    for (int k = 0; k < 256; k++) {
      float w = b2f(a.WhK[k * 256 + tid]);
      a0 += w * b2f(hsh[0][k]);
      a1 += w * b2f(hsh[1][k]);
      a2 += w * b2f(hsh[2][k]);
      a3 += w * b2f(hsh[3][k]);
    }
    hwL[0][tid] = a0;
    hwL[1][tid] = a1;
    hwL[2][tid] = a2;
    hwL[3][tid] = a3;
  }
  __syncthreads();
  // energies: wave w owns row w; lane covers 4 contiguous cols
  {
    float vv[4], hw4[4];
#pragma unroll
    for (int e = 0; e < 4; e++) {
      vv[e] = ldp(a.v, lane * 4 + e, isf32);
      hw4[e] = hwL[wave][lane * 4 + e];
    }
    const short* pb =
        (const short*)a.proj + (size_t)(b0 + wave) * 6144 + lane * 4;
    short4v p4s[24];
#pragma unroll
    for (int s = 0; s < 24; s++) p4s[s] = *(const short4v*)(pb + s * 256);
#pragma unroll
    for (int s = 0; s < 24; s++) {
      float t = 0.f;
#pragma unroll
      for (int e = 0; e < 4; e++) t += vv[e] * tanhf(hw4[e] + b2f(p4s[s][e]));
#pragma unroll
      for (int off = 1; off < 64; off <<= 1) t += __shfl_xor(t, off, 64);
      if (lane == 0) esc[wave][s] = t;
    }
  }
  __syncthreads();
  // softmax: wave w handles its own row (butterfly over lanes 0-23)
  {
    float xv = (lane < 24) ? esc[wave][lane] : -1e30f;
    float mx = xv;
#pragma unroll
    for (int off = 1; off < 64; off <<= 1)
      mx = fmaxf(mx, __shfl_xor(mx, off, 64));
    float e = (lane < 24) ? expf(xv - mx) : 0.f;
    float sm = e;
#pragma unroll
    for (int off = 1; off < 64; off <<= 1) sm += __shfl_xor(sm, off, 64);
    if (lane < 24) aw[wave][lane] = e / sm;
  }
  __syncthreads();
  // weighted sum: thread owns packed cols 2*tid for each of 4 rows
#pragma unroll
  for (int r = 0; r < 4; r++) {
    const short* eb = (const short*)a.bse + (size_t)(b0 + r) * 12288 + tid * 2;
    float w0 = 0.f, w1 = 0.f;
#pragma unroll
    for (int s = 0; s < 24; s++) {
      unsigned q = *(const unsigned*)(eb + s * 512);
      float aa = aw[r][s];
      w0 += aa * b2f((short)(q & 0xffff));
      w1 += aa * b2f((short)(q >> 16));
    }
    unsigned o = ((unsigned)(unsigned short)f2b(w1) << 16) |
                 (unsigned)(unsigned short)f2b(w0);
    *(unsigned*)((short*)a.xr + (size_t)(b0 + r) * 768 + tid * 2) = o;
  }
}

// ---- decoder cell: dual-GEMM (gi_dyn K=512 + gh K=256, separate accs;
// n-gate needs them apart) + fused GRU cell. grid (8,16). ----
struct C2Args {
  const bf16* xr;      // [2048][768] weighted at cols 0:512
  const bf16* hprev;   // [2048][256] bf16
  const short* W7p;    // [1024][512] dec_Wih[300:812]^T perm
  const short* WhhP;   // [1024][256] dec_Whh^T perm
  const bf16* bhhP;    // [1024] dec_bhh perm
  const int* tok;
  const bf16* giTabE;  // [128][768] emb@Wih[0:300]+bih
  float* hF;           // [2048][256] f32, in-place (owner-only access)
  bf16* hnext;         // [2048][256]
  bf16* xout;          // xgcAll t slice base (stride 768), cols 512:768
};

__device__ __forceinline__ void tile_acc3(const short* abase,
                                          const short* bbase, int K,
                                          short (*As)[40], short (*Bs)[40],
                                          int srow, int skoff, int wr,
                                          int wcq, int lane, f32x4 acc[4][3]) {
  short8 a0 = *(const short8*)(abase);
  short8 a1 = *(const short8*)(abase + 8);
  short8 b0 = *(const short8*)(bbase);
  short8 b1 = *(const short8*)(bbase + 8);
  for (int k0 = 0; k0 < K; k0 += 32) {
    __syncthreads();
    *(short8*)&As[srow][skoff] = a0;
    *(short8*)&As[srow][skoff + 8] = a1;
    *(short8*)&Bs[srow][skoff] = b0;
    *(short8*)&Bs[srow][skoff + 8] = b1;
    __syncthreads();
    int kn = (k0 + 32 < K) ? k0 + 32 : k0;  // clamped prefetch
    a0 = *(const short8*)(abase + kn);
    a1 = *(const short8*)(abase + kn + 8);
    b0 = *(const short8*)(bbase + kn);
    b1 = *(const short8*)(bbase + kn + 8);
    short8 af[4], bfr[3];
#pragma unroll
    for (int i = 0; i < 4; i++)
      af[i] = *(short8*)&As[wr + i * 16 + (lane & 15)][(lane >> 4) * 8];
#pragma unroll
    for (int j = 0; j < 3; j++)  // j=3 is gate-pad (zeros), skip
      bfr[j] = *(short8*)&Bs[wcq + j * 16 + (lane & 15)][(lane >> 4) * 8];
#pragma unroll
    for (int i = 0; i < 4; i++)
#pragma unroll
      for (int j = 0; j < 3; j++) acc[i][j] = MFMA(af[i], bfr[j], acc[i][j]);
  }
}

__global__ __launch_bounds__(256) void cell2_kernel(C2Args a) {
  const int n0 = blockIdx.x * 128, m0 = blockIdx.y * 128;
  __shared__ short As[128][40];
  __shared__ short Bs[128][40];
  __shared__ int toks[128];
  const int tid = threadIdx.x, lane = tid & 63, wave = tid >> 6;
  const int srow = tid >> 1, skoff = (tid & 1) * 16;
  const int wr = (wave >> 1) * 64, wcq = (wave & 1) * 64;
  if (tid < 128) toks[tid] = a.tok[m0 + tid];

  f32x4 accA[4][3], accB[4][3];
#pragma unroll
  for (int i = 0; i < 4; i++)
#pragma unroll
    for (int j = 0; j < 3; j++) {
      accA[i][j] = 0.f;
      accB[i][j] = 0.f;
    }
  // phase 1: gi_dyn = weighted @ W7p^T, K=512
  tile_acc3((const short*)a.xr + (long long)(m0 + srow) * 768 + skoff,
            a.W7p + (long long)(n0 + srow) * 512 + skoff, 512, As, Bs, srow,
            skoff, wr, wcq, lane, accA);
  // phase 2: gh = h_prev @ WhhP^T, K=256
  tile_acc3((const short*)a.hprev + (long long)(m0 + srow) * 256 + skoff,
            a.WhhP + (long long)(n0 + srow) * 256 + skoff, 256, As, Bs, srow,
            skoff, wr, wcq, lane, accB);

  const int u = lane & 15, hi4 = (lane >> 4) * 4;
  const int i_h = ((n0 + wcq) >> 6) * 16 + u;
  const float b0g = to_f(a.bhhP[n0 + wcq + u]);
  const float b1g = to_f(a.bhhP[n0 + wcq + 16 + u]);
  const float b2g = to_f(a.bhhP[n0 + wcq + 32 + u]);
#pragma unroll
  for (int i = 0; i < 4; i++) {
#pragma unroll
    for (int r = 0; r < 4; r++) {
      int row = m0 + wr + i * 16 + hi4 + r;
      const bf16* gi = a.giTabE + (long long)toks[row - m0] * 768 + i_h;
      float ir = accA[i][0][r] + to_f(gi[0]);
      float iz = accA[i][1][r] + to_f(gi[256]);
      float in_ = accA[i][2][r] + to_f(gi[512]);
      float hr = accB[i][0][r] + b0g;
      float hz = accB[i][1][r] + b1g;
      float hn = accB[i][2][r] + b2g;
      long long hidx = (long long)row * 256 + i_h;
      float hv = a.hF[hidx];
      float rr = 1.f / (1.f + expf(-(ir + hr)));
      float zz = 1.f / (1.f + expf(-(iz + hz)));
      float nn = tanhf(in_ + rr * hn);
      float o = (1.f - zz) * nn + zz * hv;
      a.hF[hidx] = o;
      a.hnext[hidx] = __float2bfloat16(o);
      a.xout[(long long)row * 768 + 512 + i_h] = __float2bfloat16(o);
    }
  }
}

__global__ void sentinel_kernel(float* out, int n) {
  int i = blockIdx.x * 256 + threadIdx.x;
  if (i < n) out[i] = 123.0f;
}

extern "C" void kernel_launch(void* const* d_in, const int* in_sizes, int n_in,
                              void* d_out, int out_size, void* d_ws,
                              size_t ws_size, hipStream_t stream) {
  const int B = 2048, S = 24, T = 25, VOUT = 128;
  const int* src = (const int*)d_in[0];
  const int* trg = (const int*)d_in[1];
  const void* enc_emb = d_in[2];
  const void* enc_Wih_f = d_in[3];
  const void* enc_Whh_f = d_in[4];
  const void* enc_bih_f = d_in[5];
  const void* enc_bhh_f = d_in[6];
  const void* enc_Wih_b = d_in[7];
  const void* enc_Whh_b = d_in[8];
  const void* enc_bih_b = d_in[9];
  const void* enc_bhh_b = d_in[10];
  const void* enc_fcW = d_in[11];
  const void* enc_fcb = d_in[12];
  const void* attn_Wh = d_in[13];
  const void* attn_We = d_in[14];
  const void* attn_b = d_in[15];
  const void* attn_v = d_in[16];
  const void* dec_emb = d_in[17];
  const void* dec_Wih = d_in[18];
  const void* dec_Whh = d_in[19];
  const void* dec_bih = d_in[20];
  const void* dec_bhh = d_in[21];
  const void* fcW = d_in[22];
  const void* fcb = d_in[23];
  float* out = (float*)d_out;

  // ---- workspace layout ----
  size_t need = 0;
  auto place = [&](size_t bytes) {
    size_t off = need;
    need += (bytes + 255) & ~(size_t)255;
    return off;
  };
  size_t o_flag = place(256);
  size_t o_wstart = need;  // memset-0 region
  size_t oEmbE = place(64 * 320 * 2);
  size_t oEmbD = place(128 * 320 * 2);
  size_t oWT1 = place(768 * 320 * 2);    // enc_Wih_f^T
  size_t oWT2 = place(1024 * 256 * 2);   // enc_Whh_f^T perm
  size_t oWT3 = place(768 * 320 * 2);    // enc_Wih_b^T
  size_t oWT4 = place(1024 * 256 * 2);   // enc_Whh_b^T perm
  size_t oWT5 = place(256 * 512 * 2);    // enc_fcW^T
  size_t oWT6 = place(256 * 512 * 2);    // attn_We^T
  size_t oWhhP = place(1024 * 256 * 2);  // dec_Whh^T perm
  size_t oWhK = place(256 * 256 * 2);    // attn_Wh row-major [k][col]
  size_t oW7aT = place(768 * 320 * 2);   // dec_Wih[0:300]^T
  size_t oW7bT = place(1024 * 512 * 2);  // dec_Wih[300:812]^T perm
  size_t oW8aT = place(128 * 320 * 2);   // fcW emb rows^T
  size_t oW8bT = place(128 * 768 * 2);   // fcW k-perm [weighted|hn]
  size_t oB1 = place(768 * 2), oB2 = place(1024 * 2);
  size_t oB3 = place(768 * 2), oB4 = place(1024 * 2);
  size_t oB5 = place(256 * 2), oB6 = place(256 * 2);
  size_t oB7 = place(768 * 2), oBcP = place(1024 * 2), oB8 = place(128 * 2);
  size_t o_wend = need;
  size_t o_bse = place((size_t)B * S * 512 * 2);
  size_t o_proj = place((size_t)B * S * 256 * 2);
  size_t o_xgc = place((size_t)(T - 1) * B * 768 * 2);  // 75.5 MB
  size_t o_hfb = place((size_t)B * 512 * 4);
  size_t o_hb0 = place((size_t)B * 512 * 2);
  size_t o_hb1 = place((size_t)B * 512 * 2);
  size_t o_hd = place((size_t)B * 256 * 4);
  size_t o_hdb0 = place((size_t)B * 256 * 2);
  size_t o_hdb1 = place((size_t)B * 256 * 2);
  size_t o_gtF = place(128 * 768 * 2);
  size_t o_gtB = place(128 * 768 * 2);
  size_t o_gtE = place(128 * 768 * 2);
  size_t o_fcT = place(128 * 128 * 4);

  if (ws_size < need) {
    sentinel_kernel<<<(out_size + 255) / 256, 256, 0, stream>>>(out, out_size);
    return;
  }

  char* base = (char*)d_ws;
  unsigned* dflag = (unsigned*)(base + o_flag);
  bf16* embE = (bf16*)(base + oEmbE);
  bf16* embD = (bf16*)(base + oEmbD);
  short* WT1 = (short*)(base + oWT1);
  short* WT2p = (short*)(base + oWT2);
  short* WT3 = (short*)(base + oWT3);
  short* WT4p = (short*)(base + oWT4);
  short* WT5 = (short*)(base + oWT5);
  short* WT6 = (short*)(base + oWT6);
  short* WhhP = (short*)(base + oWhhP);
  short* WhK = (short*)(base + oWhK);
  short* W7aT = (short*)(base + oW7aT);
  short* W7bTp = (short*)(base + oW7bT);
  short* W8aT = (short*)(base + oW8aT);
  short* W8bT = (short*)(base + oW8bT);
  bf16 *B1 = (bf16*)(base + oB1), *B2p = (bf16*)(base + oB2);
  bf16 *B3 = (bf16*)(base + oB3), *B4p = (bf16*)(base + oB4);
  bf16 *B5 = (bf16*)(base + oB5), *B6 = (bf16*)(base + oB6);
  bf16 *B7 = (bf16*)(base + oB7), *BcP = (bf16*)(base + oBcP);
  bf16* B8 = (bf16*)(base + oB8);
  bf16* bse = (bf16*)(base + o_bse);
  bf16* proj = (bf16*)(base + o_proj);
  bf16* xgcAll = (bf16*)(base + o_xgc);
  float* hfb = (float*)(base + o_hfb);
  bf16* hb[2] = {(bf16*)(base + o_hb0), (bf16*)(base + o_hb1)};
  float* h_d = (float*)(base + o_hd);
  bf16* hdbf[2] = {(bf16*)(base + o_hdb0), (bf16*)(base + o_hdb1)};
  bf16* giTabF = (bf16*)(base + o_gtF);
  bf16* giTabB = (bf16*)(base + o_gtB);
  bf16* giTabE = (bf16*)(base + o_gtE);
  float* fcTab = (float*)(base + o_fcT);

  detect_kernel<<<1, 256, 0, stream>>>(enc_emb, dflag);
  (void)hipMemsetAsync(base + o_wstart, 0, o_wend - o_wstart, stream);

  // ---- weight prep (24 segs exactly) ----
  PrepArgs pa;
  int ns = 0;
  long long tot = 0;
  auto seg = [&](const void* s, long long soff, short* dst, int scols,
                 int dstride, int transp, long long count) {
    pa.src[ns] = s;
    pa.soff[ns] = soff;
    pa.dst[ns] = dst;
    pa.scols[ns] = scols;
    pa.dstride[ns] = dstride;
    pa.transp[ns] = transp;
    pa.prefix[ns] = tot;
    tot += count;
    ns++;
  };
  seg(enc_emb, 0, (short*)embE, 300, 320, 0, 64 * 300);
  seg(dec_emb, 0, (short*)embD, 300, 320, 0, 128 * 300);
  seg(enc_Wih_f, 0, WT1, 768, 320, 1, 230400);
  seg(enc_Whh_f, 0, WT2p, 768, 256, 2, 196608);
  seg(enc_Wih_b, 0, WT3, 768, 320, 1, 230400);
  seg(enc_Whh_b, 0, WT4p, 768, 256, 2, 196608);
  seg(enc_fcW, 0, WT5, 256, 512, 1, 131072);
  seg(attn_We, 0, WT6, 256, 512, 1, 131072);
  seg(dec_Whh, 0, WhhP, 768, 256, 2, 196608);
  seg(attn_Wh, 0, WhK, 256, 256, 0, 65536);  // keep row-major [k][col]
  seg(dec_Wih, 0, W7aT, 768, 320, 1, 300 * 768);                      // 0:300
  seg(dec_Wih, (long long)300 * 768, W7bTp, 768, 512, 2, 512 * 768);  // rest
  seg(fcW, (long long)768 * 128, W8aT, 128, 320, 1, 300 * 128);  // emb
  seg(fcW, (long long)256 * 128, W8bT, 128, 768, 1, 512 * 128);  // weighted
  seg(fcW, 0, W8bT + 512, 128, 768, 1, 256 * 128);               // hn
  seg(enc_bih_f, 0, (short*)B1, 768, 768, 0, 768);
  seg(enc_bhh_f, 0, (short*)B2p, 768, 1024, 3, 768);
  seg(enc_bih_b, 0, (short*)B3, 768, 768, 0, 768);
  seg(enc_bhh_b, 0, (short*)B4p, 768, 1024, 3, 768);
  seg(enc_fcb, 0, (short*)B5, 256, 256, 0, 256);
  seg(attn_b, 0, (short*)B6, 256, 256, 0, 256);
  seg(dec_bih, 0, (short*)B7, 768, 768, 0, 768);
  seg(dec_bhh, 0, (short*)BcP, 768, 1024, 3, 768);
  seg(fcb, 0, (short*)B8, 128, 128, 0, 128);
  pa.prefix[ns] = tot;
  pa.nseg = ns;
  prep_kernel<<<(int)((tot + 255) / 256), 256, 0, stream>>>(pa, dflag);

  (void)hipMemsetAsync(hfb, 0, (size_t)B * 512 * 4, stream);
  (void)hipMemsetAsync(hb[0], 0, (size_t)B * 512 * 2, stream);
  (void)hipMemsetAsync(out, 0, (size_t)B * VOUT * 4, stream);  // outputs[0]=0

  auto launch = [&](const GJob* jobs, int nj, int gx, int gy) {
    GJobs a{};
    for (int i = 0; i < nj; i++) a.j[i] = jobs[i];
    mj_gemm<<<dim3(gx, gy, nj), 256, 0, stream>>>(a);
  };

  // ---- token tables ----
  {
    GJob tj[4];
    tj[0] = {embE, WT1, B1, nullptr, giTabF, nullptr, nullptr,
             320, 320, 320, 128, 768, 0};
    tj[1] = {embE, WT3, B3, nullptr, giTabB, nullptr, nullptr,
             320, 320, 320, 128, 768, 0};
    tj[2] = {embD, W7aT, B7, nullptr, giTabE, nullptr, nullptr,
             320, 320, 320, 128, 768, 0};
    tj[3] = {embD, W8aT, B8, fcTab, nullptr, nullptr, nullptr,
             320, 320, 320, 128, 128, 0};
    launch(tj, 4, 6, 1);
  }

  // ---- encoder: one fused launch per step ----
  for (int s = 0; s < S; s++) {
    CJobs ca{};
    ca.j[0] = {hb[s & 1], WT2p, B2p, src + (size_t)s * B, giTabF,
               hfb, hb[(s + 1) & 1], bse + (size_t)s * 512, 12288,
               512, 256, 256, 512, 0};
    ca.j[1] = {hb[s & 1] + 256, WT4p, B4p, src + (size_t)(S - 1 - s) * B,
               giTabB, hfb, hb[(s + 1) & 1],
               bse + (size_t)(S - 1 - s) * 512 + 256, 12288,
               512, 256, 256, 512, 256};
    mj_gemm_cell<<<dim3(8, 16, 2), 256, 0, stream>>>(ca);
  }

  // ---- mid: hidden (h_d + hdbf0) and proj, one launch ----
  {
    GJob mj[2];
    mj[0] = {hb[0], WT5, B5, h_d, hdbf[0], nullptr, nullptr,
             512, 512, 512, B, 256, 4};
    mj[1] = {bse, WT6, B6, nullptr, proj, nullptr, nullptr,
             512, 512, 512, B * S, 256, 0};
    launch(mj, 2, 2, 384);
  }

  // ---- decoder: 2 launches per step (attn4 w/ fused hwh, cell2) ----
  for (int t = 0; t < T - 1; t++) {
    bf16* xr = xgcAll + (size_t)t * B * 768;
    A4Args aa{hdbf[t & 1], WhK, proj, bse, attn_v, dflag, xr};
    attn4_kernel<<<512, 256, 0, stream>>>(aa);
    C2Args cc{xr,    hdbf[t & 1], W7bTp, WhhP, BcP,
              trg + (size_t)t * B, giTabE, h_d, hdbf[(t + 1) & 1], xr};
    cell2_kernel<<<dim3(8, 16), 256, 0, stream>>>(cc);
  }

  // ---- logits for all steps, batched ----
  {
    GJob jf = {xgcAll, W8bT, nullptr, out + (size_t)B * VOUT, nullptr,
               fcTab, trg, 768, 768, 768, (T - 1) * B, 128, 0};
    launch(&jf, 1, 1, 384);
  }
}

// Round 12
// 1793.811 us; speedup vs baseline: 1.1931x; 1.1931x over previous
//
#include <hip/hip_runtime.h>
#include <hip/hip_bf16.h>

typedef __hip_bfloat16 bf16;
typedef __attribute__((ext_vector_type(8))) short short8;
typedef __attribute__((ext_vector_type(4))) short short4v;
typedef __attribute__((ext_vector_type(4))) float f32x4;

#define MFMA(va, vb, vc) \
  __builtin_amdgcn_mfma_f32_16x16x32_bf16(va, vb, vc, 0, 0, 0)

__device__ __forceinline__ float to_f(float x) { return x; }
__device__ __forceinline__ float to_f(bf16 x) { return __bfloat162float(x); }
__device__ __forceinline__ float ldp(const void* p, size_t i, bool f32) {
  return f32 ? ((const float*)p)[i] : __bfloat162float(((const bf16*)p)[i]);
}
__device__ __forceinline__ short f2b(float f) {
  bf16 h = __float2bfloat16(f);
  return *reinterpret_cast<short*>(&h);
}
__device__ __forceinline__ float b2f(short s_) {
  unsigned int ui = ((unsigned int)(unsigned short)s_) << 16;
  float f;
  __builtin_memcpy(&f, &ui, 4);
  return f;
}
// gate-interleave permutation: c = g*256+i -> 64*(i>>4) + 16*g + (i&15).
// MFMA n-subtile j == gate in fused cell kernels.
__device__ __forceinline__ int perm1024(int c) {
  return ((c & 255) >> 4) * 64 + (c >> 8) * 16 + (c & 15);
}

// dtype probe: f32 data read as u16 pairs shows implausible bf16 exponents.
__global__ void detect_kernel(const void* __restrict__ probe,
                              unsigned* __restrict__ flag) {
  __shared__ int sbad;
  if (threadIdx.x == 0) sbad = 0;
  __syncthreads();
  const unsigned short* u = (const unsigned short*)probe;
  int bad = 0;
  for (int i = threadIdx.x; i < 2048; i += 256) {
    unsigned short w = u[i];
    unsigned e = (w >> 7) & 0xFFu;
    bool plaus = (w == 0) || (w == 0x8000u) || (e >= 0x60u && e <= 0x7Eu);
    if (!plaus) bad++;
  }
  atomicAdd(&sbad, bad);
  __syncthreads();
  if (threadIdx.x == 0) *flag = (sbad > 100) ? 1u : 0u;
}

// ---- weight prep ----
// transp: 0=copy, 1=transpose, 2=transpose+perm1024, 3=copy+perm1024
#define MAXSEG 24
struct PrepArgs {
  int nseg;
  const void* src[MAXSEG];
  long long soff[MAXSEG];
  short* dst[MAXSEG];
  int scols[MAXSEG];
  int dstride[MAXSEG];
  int transp[MAXSEG];
  long long prefix[MAXSEG + 1];
};
__global__ void prep_kernel(PrepArgs a, const unsigned* __restrict__ dflag) {
  const bool isf32 = (*dflag != 0u);
  long long i = (long long)blockIdx.x * 256 + threadIdx.x;
  if (i >= a.prefix[a.nseg]) return;
  int s = 0;
  while (i >= a.prefix[s + 1]) s++;
  long long loc = i - a.prefix[s];
  long long r = loc / a.scols[s], c = loc % a.scols[s];
  float v = a.src[s] ? ldp(a.src[s], (size_t)(a.soff[s] + loc), isf32) : 0.f;
  int tp = a.transp[s];
  long long idx;
  if (tp == 1)
    idx = c * a.dstride[s] + r;
  else if (tp == 2)
    idx = (long long)perm1024((int)c) * a.dstride[s] + r;
  else if (tp == 3)
    idx = perm1024((int)c);
  else
    idx = r * a.dstride[s] + c;
  a.dst[s][idx] = f2b(v);
}

// ---- multi-job MFMA GEMM, 128x128 tile (tables, mid, wcjh, logits) ----
struct GJob {
  const bf16* A;
  const short* WT;
  const bf16* bias;
  float* Cf;
  bf16* Ch;
  const float* Cin;   // optional f32 addend, stride N
  const int* cinrow;  // optional row gather for Cin
  int lda, wst, K, M, N, flags;  // flags: 4=tanh
};
struct GJobs {
  GJob j[4];
};

__global__ __launch_bounds__(256) void mj_gemm(GJobs args) {
  GJob jb = args.j[blockIdx.z];
  const int n0 = blockIdx.x * 128, m0 = blockIdx.y * 128;
  if (n0 >= jb.N || m0 >= jb.M) return;
  __shared__ short As[128][40];
  __shared__ short Bs[128][40];
  const int tid = threadIdx.x, lane = tid & 63, wave = tid >> 6;
  const int srow = tid >> 1, skoff = (tid & 1) * 16;
  const int wr = (wave >> 1) * 64, wc = (wave & 1) * 64;

  const short* abase =
      (const short*)jb.A + (long long)(m0 + srow) * jb.lda + skoff;
  const short* bbase = jb.WT + (long long)(n0 + srow) * jb.wst + skoff;
  f32x4 acc[4][4];
#pragma unroll
  for (int i = 0; i < 4; i++)
#pragma unroll
    for (int j = 0; j < 4; j++) acc[i][j] = 0.f;

  short8 a0 = *(const short8*)(abase);
  short8 a1 = *(const short8*)(abase + 8);
  short8 b0 = *(const short8*)(bbase);
  short8 b1 = *(const short8*)(bbase + 8);
  for (int k0 = 0; k0 < jb.K; k0 += 32) {
    __syncthreads();
    *(short8*)&As[srow][skoff] = a0;
    *(short8*)&As[srow][skoff + 8] = a1;
    *(short8*)&Bs[srow][skoff] = b0;
    *(short8*)&Bs[srow][skoff + 8] = b1;
    __syncthreads();
    int kn = (k0 + 32 < jb.K) ? k0 + 32 : k0;  // clamped prefetch
    a0 = *(const short8*)(abase + kn);
    a1 = *(const short8*)(abase + kn + 8);
    b0 = *(const short8*)(bbase + kn);
    b1 = *(const short8*)(bbase + kn + 8);
    short8 af[4], bfr[4];
#pragma unroll
    for (int i = 0; i < 4; i++)
      af[i] = *(short8*)&As[wr + i * 16 + (lane & 15)][(lane >> 4) * 8];
#pragma unroll
    for (int j = 0; j < 4; j++)
      bfr[j] = *(short8*)&Bs[wc + j * 16 + (lane & 15)][(lane >> 4) * 8];
#pragma unroll
    for (int i = 0; i < 4; i++)
#pragma unroll
      for (int j = 0; j < 4; j++) acc[i][j] = MFMA(af[i], bfr[j], acc[i][j]);
  }
  const int N = jb.N;
  const float* cin = jb.Cin;
  const int* cri = jb.cinrow;
#pragma unroll
  for (int j = 0; j < 4; j++) {
    int col = n0 + wc + j * 16 + (lane & 15);
    float bv = jb.bias ? to_f(jb.bias[col]) : 0.f;
#pragma unroll
    for (int i = 0; i < 4; i++) {
#pragma unroll
      for (int r = 0; r < 4; r++) {
        int row = m0 + wr + i * 16 + (lane >> 4) * 4 + r;
        float v = acc[i][j][r] + bv;
        if (cin) {
          long long crow = cri ? (long long)cri[row] : (long long)row;
          v += cin[crow * N + col];
        }
        if (jb.flags & 4) v = tanhf(v);
        if (jb.Cf) jb.Cf[(long long)row * N + col] = v;
        if (jb.Ch) jb.Ch[(long long)row * N + col] = __float2bfloat16(v);
      }
    }
  }
}

// ---- encoder fused GEMM + GRU cell (round-2 proven kernel) ----
struct CJob {
  const bf16* A;
  const short* WT;
  const bf16* bias;
  const int* tok;
  const bf16* giTab;  // [vocab][768] gate-major (incl bih)
  float* hF;
  bf16* hBf;
  bf16* out2;  // bse slice
  long long out2s;
  int lda, wst, K, hstride, hoff;
};
struct CJobs {
  CJob j[2];
};

__global__ __launch_bounds__(256) void mj_gemm_cell(CJobs args) {
  CJob jb = args.j[blockIdx.z];
  const int n0 = blockIdx.x * 128, m0 = blockIdx.y * 128;
  __shared__ short As[128][40];
  __shared__ short Bs[128][40];
  __shared__ int toks[128];
  const int tid = threadIdx.x, lane = tid & 63, wave = tid >> 6;
  const int srow = tid >> 1, skoff = (tid & 1) * 16;
  const int wr = (wave >> 1) * 64, wcq = (wave & 1) * 64;

  if (tid < 128) toks[tid] = jb.tok[m0 + tid];
  const short* abase =
      (const short*)jb.A + (long long)(m0 + srow) * jb.lda + skoff;
  const short* bbase = jb.WT + (long long)(n0 + srow) * jb.wst + skoff;

  f32x4 acc[4][4];
#pragma unroll
  for (int i = 0; i < 4; i++)
#pragma unroll
    for (int j = 0; j < 4; j++) acc[i][j] = 0.f;

  short8 a0 = *(const short8*)(abase);
  short8 a1 = *(const short8*)(abase + 8);
  short8 b0 = *(const short8*)(bbase);
  short8 b1 = *(const short8*)(bbase + 8);
  for (int k0 = 0; k0 < jb.K; k0 += 32) {
    __syncthreads();
    *(short8*)&As[srow][skoff] = a0;
    *(short8*)&As[srow][skoff + 8] = a1;
    *(short8*)&Bs[srow][skoff] = b0;
    *(short8*)&Bs[srow][skoff + 8] = b1;
    __syncthreads();
    int kn = (k0 + 32 < jb.K) ? k0 + 32 : k0;
    a0 = *(const short8*)(abase + kn);
    a1 = *(const short8*)(abase + kn + 8);
    b0 = *(const short8*)(bbase + kn);
    b1 = *(const short8*)(bbase + kn + 8);
    short8 af[4], bfr[4];
#pragma unroll
    for (int i = 0; i < 4; i++)
      af[i] = *(short8*)&As[wr + i * 16 + (lane & 15)][(lane >> 4) * 8];
#pragma unroll
    for (int j = 0; j < 4; j++)
      bfr[j] = *(short8*)&Bs[wcq + j * 16 + (lane & 15)][(lane >> 4) * 8];
#pragma unroll
    for (int i = 0; i < 4; i++)
#pragma unroll
      for (int j = 0; j < 4; j++) acc[i][j] = MFMA(af[i], bfr[j], acc[i][j]);
  }

  const int u = lane & 15, hi4 = (lane >> 4) * 4;
  const int i_h = ((n0 + wcq) >> 6) * 16 + u;
  const float b0g = to_f(jb.bias[n0 + wcq + u]);
  const float b1g = to_f(jb.bias[n0 + wcq + 16 + u]);
  const float b2g = to_f(jb.bias[n0 + wcq + 32 + u]);
#pragma unroll
  for (int i = 0; i < 4; i++) {
#pragma unroll
    for (int r = 0; r < 4; r++) {
      int row = m0 + wr + i * 16 + hi4 + r;
      const bf16* gi = jb.giTab + (long long)toks[row - m0] * 768 + i_h;
      float ir = to_f(gi[0]), iz = to_f(gi[256]), in_ = to_f(gi[512]);
      float hr = acc[i][0][r] + b0g;
      float hz = acc[i][1][r] + b1g;
      float hn = acc[i][2][r] + b2g;
      long long hidx = (long long)row * jb.hstride + jb.hoff + i_h;
      float hv = jb.hF[hidx];
      float rr = 1.f / (1.f + expf(-(ir + hr)));
      float zz = 1.f / (1.f + expf(-(iz + hz)));
      float nn = tanhf(in_ + rr * hn);
      float o = (1.f - zz) * nn + zz * hv;
      jb.hF[hidx] = o;
      jb.hBf[hidx] = __float2bfloat16(o);
      jb.out2[(long long)row * jb.out2s + i_h] = __float2bfloat16(o);
    }
  }
}

// ---- attention v3 (round-10 proven): one block per batch row; hwh read
// from ghw cols 1024:1280 (precomputed by the wcjh GEMM). ----
struct A3Args {
  const bf16* ghw;   // [2048][1280]: perm gh at 0:1024, hwh at 1024:1280
  const bf16* proj;  // [2048*24][256] includes attn_b
  const bf16* bse;   // [2048][24*512]
  const void* v;
  const unsigned* dflag;
  bf16* xr;  // xgcAll t slice base, stride 768, writes cols 0:512
};
__global__ __launch_bounds__(256) void attn3_kernel(A3Args a) {
  const int b = blockIdx.x, tid = threadIdx.x;
  const int wave = tid >> 6, lane = tid & 63;
  __shared__ float esc[24];
  __shared__ float aw[24];
  const bool isf32 = (*a.dflag != 0u);
  // lane covers 4 contiguous cols: lane*4 .. lane*4+3
  float vv[4], hw[4];
  {
    short4v h4 = *(const short4v*)((const short*)a.ghw + (size_t)b * 1280 +
                                   1024 + lane * 4);
#pragma unroll
    for (int e = 0; e < 4; e++) {
      hw[e] = b2f(h4[e]);
      vv[e] = ldp(a.v, lane * 4 + e, isf32);
    }
  }
  // energies: wave w owns s = w*6 .. w*6+5; prefetch all 6 rows
  const short* pb = (const short*)a.proj + (size_t)b * 6144 + lane * 4;
  short4v p4s[6];
#pragma unroll
  for (int i = 0; i < 6; i++)
    p4s[i] = *(const short4v*)(pb + (wave * 6 + i) * 256);
#pragma unroll
  for (int i = 0; i < 6; i++) {
    float t = 0.f;
#pragma unroll
    for (int e = 0; e < 4; e++)
      t += vv[e] * tanhf(hw[e] + b2f(p4s[i][e]));
#pragma unroll
    for (int off = 1; off < 64; off <<= 1) t += __shfl_xor(t, off, 64);
    if (lane == 0) esc[wave * 6 + i] = t;
  }
  __syncthreads();
  if (wave == 0) {
    float xv = (lane < 24) ? esc[lane] : -1e30f;
    float mx = xv;
#pragma unroll
    for (int off = 1; off < 64; off <<= 1)
      mx = fmaxf(mx, __shfl_xor(mx, off, 64));
    float e = (lane < 24) ? expf(xv - mx) : 0.f;
    float sm = e;
#pragma unroll
    for (int off = 1; off < 64; off <<= 1) sm += __shfl_xor(sm, off, 64);
    if (lane < 24) aw[lane] = e / sm;
  }
  __syncthreads();
  // weighted sum: thread owns packed cols 2*tid, 2*tid+1
  const short* eb = (const short*)a.bse + (size_t)b * 12288 + tid * 2;
  float w0 = 0.f, w1 = 0.f;
#pragma unroll
  for (int s = 0; s < 24; s++) {
    unsigned q = *(const unsigned*)(eb + s * 512);
    float aa = aw[s];
    w0 += aa * b2f((short)(q & 0xffff));
    w1 += aa * b2f((short)(q >> 16));
  }
  unsigned o = ((unsigned)(unsigned short)f2b(w1) << 16) |
               (unsigned)(unsigned short)f2b(w0);
  *(unsigned*)((short*)a.xr + (size_t)b * 768 + tid * 2) = o;
}

// ---- decoder cell v3: single K=512 GEMM (gi_dyn); gh read from ghw
// (precomputed off the attention critical path). grid (8,16). ----
struct C3Args {
  const bf16* xr;      // [2048][768] weighted at cols 0:512
  const bf16* ghw;     // [2048][1280]: perm gh at 0:1024
  const short* W7p;    // [1024][512] dec_Wih[300:812]^T perm
  const bf16* bhhP;    // [1024] dec_bhh perm
  const int* tok;
  const bf16* giTabE;  // [128][768] emb@Wih[0:300]+bih
  float* hF;           // [2048][256] f32, in-place (owner-only access)
  bf16* hnext;         // [2048][256]
  bf16* xout;          // xgcAll t slice base (stride 768), cols 512:768
};

__global__ __launch_bounds__(256) void cell3_kernel(C3Args a) {
  const int n0 = blockIdx.x * 128, m0 = blockIdx.y * 128;
  __shared__ short As[128][40];
  __shared__ short Bs[128][40];
  __shared__ int toks[128];
  const int tid = threadIdx.x, lane = tid & 63, wave = tid >> 6;
  const int srow = tid >> 1, skoff = (tid & 1) * 16;
  const int wr = (wave >> 1) * 64, wcq = (wave & 1) * 64;
  if (tid < 128) toks[tid] = a.tok[m0 + tid];

  f32x4 acc[4][3];
#pragma unroll
  for (int i = 0; i < 4; i++)
#pragma unroll
    for (int j = 0; j < 3; j++) acc[i][j] = 0.f;

  // gi_dyn = weighted @ W7p^T, K=512 (j=3 n-subtile is gate-pad, skipped)
  {
    const short* abase =
        (const short*)a.xr + (long long)(m0 + srow) * 768 + skoff;
    const short* bbase = a.W7p + (long long)(n0 + srow) * 512 + skoff;
    short8 a0 = *(const short8*)(abase);
    short8 a1 = *(const short8*)(abase + 8);
    short8 b0 = *(const short8*)(bbase);
    short8 b1 = *(const short8*)(bbase + 8);
    for (int k0 = 0; k0 < 512; k0 += 32) {
      __syncthreads();
      *(short8*)&As[srow][skoff] = a0;
      *(short8*)&As[srow][skoff + 8] = a1;
      *(short8*)&Bs[srow][skoff] = b0;
      *(short8*)&Bs[srow][skoff + 8] = b1;
      __syncthreads();
      int kn = (k0 + 32 < 512) ? k0 + 32 : k0;  // clamped prefetch
      a0 = *(const short8*)(abase + kn);
      a1 = *(const short8*)(abase + kn + 8);
      b0 = *(const short8*)(bbase + kn);
      b1 = *(const short8*)(bbase + kn + 8);
      short8 af[4], bfr[3];
#pragma unroll
      for (int i = 0; i < 4; i++)
        af[i] = *(short8*)&As[wr + i * 16 + (lane & 15)][(lane >> 4) * 8];
#pragma unroll
      for (int j = 0; j < 3; j++)
        bfr[j] = *(short8*)&Bs[wcq + j * 16 + (lane & 15)][(lane >> 4) * 8];
#pragma unroll
      for (int i = 0; i < 4; i++)
#pragma unroll
        for (int j = 0; j < 3; j++) acc[i][j] = MFMA(af[i], bfr[j], acc[i][j]);
    }
  }

  const int u = lane & 15, hi4 = (lane >> 4) * 4;
  const int i_h = ((n0 + wcq) >> 6) * 16 + u;
  const float b0g = to_f(a.bhhP[n0 + wcq + u]);
  const float b1g = to_f(a.bhhP[n0 + wcq + 16 + u]);
  const float b2g = to_f(a.bhhP[n0 + wcq + 32 + u]);
#pragma unroll
  for (int i = 0; i < 4; i++) {
#pragma unroll
    for (int r = 0; r < 4; r++) {
      int row = m0 + wr + i * 16 + hi4 + r;
      const bf16* gi = a.giTabE + (long long)toks[row - m0] * 768 + i_h;
      // gh gates for hidden i_h live at ghw cols (n0+wcq)+u, +16, +32
      const bf16* gb = a.ghw + (long long)row * 1280 + (n0 + wcq) + u;
      float ir = acc[i][0][r] + to_f(gi[0]);
      float iz = acc[i][1][r] + to_f(gi[256]);
      float in_ = acc[i][2][r] + to_f(gi[512]);
      float hr = to_f(gb[0]) + b0g;
      float hz = to_f(gb[16]) + b1g;
      float hn = to_f(gb[32]) + b2g;
      long long hidx = (long long)row * 256 + i_h;
      float hv = a.hF[hidx];
      float rr = 1.f / (1.f + expf(-(ir + hr)));
      float zz = 1.f / (1.f + expf(-(iz + hz)));
      float nn = tanhf(in_ + rr * hn);
      float o = (1.f - zz) * nn + zz * hv;
      a.hF[hidx] = o;
      a.hnext[hidx] = __float2bfloat16(o);
      a.xout[(long long)row * 768 + 512 + i_h] = __float2bfloat16(o);
    }
  }
}

__global__ void sentinel_kernel(float* out, int n) {
  int i = blockIdx.x * 256 + threadIdx.x;
  if (i < n) out[i] = 123.0f;
}

extern "C" void kernel_launch(void* const* d_in, const int* in_sizes, int n_in,
                              void* d_out, int out_size, void* d_ws,
                              size_t ws_size, hipStream_t stream) {
  const int B = 2048, S = 24, T = 25, VOUT = 128;
  const int* src = (const int*)d_in[0];
  const int* trg = (const int*)d_in[1];
  const void* enc_emb = d_in[2];
  const void* enc_Wih_f = d_in[3];
  const void* enc_Whh_f = d_in[4];
  const void* enc_bih_f = d_in[5];
  const void* enc_bhh_f = d_in[6];
  const void* enc_Wih_b = d_in[7];
  const void* enc_Whh_b = d_in[8];
  const void* enc_bih_b = d_in[9];
  const void* enc_bhh_b = d_in[10];
  const void* enc_fcW = d_in[11];
  const void* enc_fcb = d_in[12];
  const void* attn_Wh = d_in[13];
  const void* attn_We = d_in[14];
  const void* attn_b = d_in[15];
  const void* attn_v = d_in[16];
  const void* dec_emb = d_in[17];
  const void* dec_Wih = d_in[18];
  const void* dec_Whh = d_in[19];
  const void* dec_bih = d_in[20];
  const void* dec_bhh = d_in[21];
  const void* fcW = d_in[22];
  const void* fcb = d_in[23];
  float* out = (float*)d_out;

  // ---- workspace layout ----
  size_t need = 0;
  auto place = [&](size_t bytes) {
    size_t off = need;
    need += (bytes + 255) & ~(size_t)255;
    return off;
  };
  size_t o_flag = place(256);
  size_t o_wstart = need;  // memset-0 region
  size_t oEmbE = place(64 * 320 * 2);
  size_t oEmbD = place(128 * 320 * 2);
  size_t oWT1 = place(768 * 320 * 2);    // enc_Wih_f^T
  size_t oWT2 = place(1024 * 256 * 2);   // enc_Whh_f^T perm
  size_t oWT3 = place(768 * 320 * 2);    // enc_Wih_b^T
  size_t oWT4 = place(1024 * 256 * 2);   // enc_Whh_b^T perm
  size_t oWT5 = place(256 * 512 * 2);    // enc_fcW^T
  size_t oWT6 = place(256 * 512 * 2);    // attn_We^T
  size_t oWcK = place(1280 * 256 * 2);   // [dec_Whh perm | attn_Wh^T]
  size_t oW7aT = place(768 * 320 * 2);   // dec_Wih[0:300]^T
  size_t oW7bT = place(1024 * 512 * 2);  // dec_Wih[300:812]^T perm
  size_t oW8aT = place(128 * 320 * 2);   // fcW emb rows^T
  size_t oW8bT = place(128 * 768 * 2);   // fcW k-perm [weighted|hn]
  size_t oB1 = place(768 * 2), oB2 = place(1024 * 2);
  size_t oB3 = place(768 * 2), oB4 = place(1024 * 2);
  size_t oB5 = place(256 * 2), oB6 = place(256 * 2);
  size_t oB7 = place(768 * 2), oBcP = place(1024 * 2), oB8 = place(128 * 2);
  size_t o_wend = need;
  size_t o_bse = place((size_t)B * S * 512 * 2);
  size_t o_proj = place((size_t)B * S * 256 * 2);
  size_t o_xgc = place((size_t)(T - 1) * B * 768 * 2);  // 75.5 MB
  size_t o_hfb = place((size_t)B * 512 * 4);
  size_t o_hb0 = place((size_t)B * 512 * 2);
  size_t o_hb1 = place((size_t)B * 512 * 2);
  size_t o_hd = place((size_t)B * 256 * 4);
  size_t o_hdb0 = place((size_t)B * 256 * 2);
  size_t o_hdb1 = place((size_t)B * 256 * 2);
  size_t o_ghw = place((size_t)B * 1280 * 2);
  size_t o_gtF = place(128 * 768 * 2);
  size_t o_gtB = place(128 * 768 * 2);
  size_t o_gtE = place(128 * 768 * 2);
  size_t o_fcT = place(128 * 128 * 4);

  if (ws_size < need) {
    sentinel_kernel<<<(out_size + 255) / 256, 256, 0, stream>>>(out, out_size);
    return;
  }

  char* base = (char*)d_ws;
  unsigned* dflag = (unsigned*)(base + o_flag);
  bf16* embE = (bf16*)(base + oEmbE);
  bf16* embD = (bf16*)(base + oEmbD);
  short* WT1 = (short*)(base + oWT1);
  short* WT2p = (short*)(base + oWT2);
  short* WT3 = (short*)(base + oWT3);
  short* WT4p = (short*)(base + oWT4);
  short* WT5 = (short*)(base + oWT5);
  short* WT6 = (short*)(base + oWT6);
  short* WcK = (short*)(base + oWcK);
  short* W7aT = (short*)(base + oW7aT);
  short* W7bTp = (short*)(base + oW7bT);
  short* W8aT = (short*)(base + oW8aT);
  short* W8bT = (short*)(base + oW8bT);
  bf16 *B1 = (bf16*)(base + oB1), *B2p = (bf16*)(base + oB2);
  bf16 *B3 = (bf16*)(base + oB3), *B4p = (bf16*)(base + oB4);
  bf16 *B5 = (bf16*)(base + oB5), *B6 = (bf16*)(base + oB6);
  bf16 *B7 = (bf16*)(base + oB7), *BcP = (bf16*)(base + oBcP);
  bf16* B8 = (bf16*)(base + oB8);
  bf16* bse = (bf16*)(base + o_bse);
  bf16* proj = (bf16*)(base + o_proj);
  bf16* xgcAll = (bf16*)(base + o_xgc);
  float* hfb = (float*)(base + o_hfb);
  bf16* hb[2] = {(bf16*)(base + o_hb0), (bf16*)(base + o_hb1)};
  float* h_d = (float*)(base + o_hd);
  bf16* hdbf[2] = {(bf16*)(base + o_hdb0), (bf16*)(base + o_hdb1)};
  bf16* ghw = (bf16*)(base + o_ghw);
  bf16* giTabF = (bf16*)(base + o_gtF);
  bf16* giTabB = (bf16*)(base + o_gtB);
  bf16* giTabE = (bf16*)(base + o_gtE);
  float* fcTab = (float*)(base + o_fcT);

  detect_kernel<<<1, 256, 0, stream>>>(enc_emb, dflag);
  (void)hipMemsetAsync(base + o_wstart, 0, o_wend - o_wstart, stream);

  // ---- weight prep (24 segs exactly) ----
  PrepArgs pa;
  int ns = 0;
  long long tot = 0;
  auto seg = [&](const void* s, long long soff, short* dst, int scols,
                 int dstride, int transp, long long count) {
    pa.src[ns] = s;
    pa.soff[ns] = soff;
    pa.dst[ns] = dst;
    pa.scols[ns] = scols;
    pa.dstride[ns] = dstride;
    pa.transp[ns] = transp;
    pa.prefix[ns] = tot;
    tot += count;
    ns++;
  };
  seg(enc_emb, 0, (short*)embE, 300, 320, 0, 64 * 300);
  seg(dec_emb, 0, (short*)embD, 300, 320, 0, 128 * 300);
  seg(enc_Wih_f, 0, WT1, 768, 320, 1, 230400);
  seg(enc_Whh_f, 0, WT2p, 768, 256, 2, 196608);
  seg(enc_Wih_b, 0, WT3, 768, 320, 1, 230400);
  seg(enc_Whh_b, 0, WT4p, 768, 256, 2, 196608);
  seg(enc_fcW, 0, WT5, 256, 512, 1, 131072);
  seg(attn_We, 0, WT6, 256, 512, 1, 131072);
  seg(dec_Whh, 0, WcK, 768, 256, 2, 196608);               // rows 0:1024 perm
  seg(attn_Wh, 0, WcK + 1024 * 256, 256, 256, 1, 65536);   // rows 1024:1280
  seg(dec_Wih, 0, W7aT, 768, 320, 1, 300 * 768);                      // 0:300
  seg(dec_Wih, (long long)300 * 768, W7bTp, 768, 512, 2, 512 * 768);  // rest
  seg(fcW, (long long)768 * 128, W8aT, 128, 320, 1, 300 * 128);  // emb
  seg(fcW, (long long)256 * 128, W8bT, 128, 768, 1, 512 * 128);  // weighted
  seg(fcW, 0, W8bT + 512, 128, 768, 1, 256 * 128);               // hn
  seg(enc_bih_f, 0, (short*)B1, 768, 768, 0, 768);
  seg(enc_bhh_f, 0, (short*)B2p, 768, 1024, 3, 768);
  seg(enc_bih_b, 0, (short*)B3, 768, 768, 0, 768);
  seg(enc_bhh_b, 0, (short*)B4p, 768, 1024, 3, 768);
  seg(enc_fcb, 0, (short*)B5, 256, 256, 0, 256);
  seg(attn_b, 0, (short*)B6, 256, 256, 0, 256);
  seg(dec_bih, 0, (short*)B7, 768, 768, 0, 768);
  seg(dec_bhh, 0, (short*)BcP, 768, 1024, 3, 768);
  seg(fcb, 0, (short*)B8, 128, 128, 0, 128);
  pa.prefix[ns] = tot;
  pa.nseg = ns;
  prep_kernel<<<(int)((tot + 255) / 256), 256, 0, stream>>>(pa, dflag);

  (void)hipMemsetAsync(hfb, 0, (size_t)B * 512 * 4, stream);
  (void)hipMemsetAsync(hb[0], 0, (size_t)B * 512 * 2, stream);
  (void)hipMemsetAsync(out, 0, (size_t)B * VOUT * 4, stream);  // outputs[0]=0

  auto launch = [&](const GJob* jobs, int nj, int gx, int gy) {
    GJobs a{};
    for (int i = 0; i < nj; i++) a.j[i] = jobs[i];
    mj_gemm<<<dim3(gx, gy, nj), 256, 0, stream>>>(a);
  };

  // ---- token tables ----
  {
    GJob tj[4];
    tj[0] = {embE, WT1, B1, nullptr, giTabF, nullptr, nullptr,
             320, 320, 320, 128, 768, 0};
    tj[1] = {embE, WT3, B3, nullptr, giTabB, nullptr, nullptr,
             320, 320, 320, 128, 768, 0};
    tj[2] = {embD, W7aT, B7, nullptr, giTabE, nullptr, nullptr,
             320, 320, 320, 128, 768, 0};
    tj[3] = {embD, W8aT, B8, fcTab, nullptr, nullptr, nullptr,
             320, 320, 320, 128, 128, 0};
    launch(tj, 4, 6, 1);
  }

  // ---- encoder: one fused launch per step ----
  for (int s = 0; s < S; s++) {
    CJobs ca{};
    ca.j[0] = {hb[s & 1], WT2p, B2p, src + (size_t)s * B, giTabF,
               hfb, hb[(s + 1) & 1], bse + (size_t)s * 512, 12288,
               512, 256, 256, 512, 0};
    ca.j[1] = {hb[s & 1] + 256, WT4p, B4p, src + (size_t)(S - 1 - s) * B,
               giTabB, hfb, hb[(s + 1) & 1],
               bse + (size_t)(S - 1 - s) * 512 + 256, 12288,
               512, 256, 256, 512, 256};
    mj_gemm_cell<<<dim3(8, 16, 2), 256, 0, stream>>>(ca);
  }

  // ---- mid: hidden (h_d + hdbf0) and proj, one launch ----
  {
    GJob mj[2];
    mj[0] = {hb[0], WT5, B5, h_d, hdbf[0], nullptr, nullptr,
             512, 512, 512, B, 256, 4};
    mj[1] = {bse, WT6, B6, nullptr, proj, nullptr, nullptr,
             512, 512, 512, B * S, 256, 0};
    launch(mj, 2, 2, 384);
  }

  // ---- decoder: wcjh GEMM (gh+hwh, off attn critical path) -> attn3 ->
  // cell3 (K=512 only) per step ----
  for (int t = 0; t < T - 1; t++) {
    bf16* xr = xgcAll + (size_t)t * B * 768;
    GJob jw = {hdbf[t & 1], WcK, nullptr, nullptr, ghw, nullptr, nullptr,
               256, 256, 256, B, 1280, 0};
    launch(&jw, 1, 10, 16);
    A3Args aa{ghw, proj, bse, attn_v, dflag, xr};
    attn3_kernel<<<B, 256, 0, stream>>>(aa);
    C3Args cc{xr, ghw, W7bTp, BcP, trg + (size_t)t * B, giTabE,
              h_d, hdbf[(t + 1) & 1], xr};
    cell3_kernel<<<dim3(8, 16), 256, 0, stream>>>(cc);
  }

  // ---- logits for all steps, batched ----
  {
    GJob jf = {xgcAll, W8bT, nullptr, out + (size_t)B * VOUT, nullptr,
               fcTab, trg, 768, 768, 768, (T - 1) * B, 128, 0};
    launch(&jf, 1, 1, 384);
  }
}